// Round 1
// baseline (2895.719 us; speedup 1.0000x reference)
//
#include <hip/hip_runtime.h>
#include <cstdint>
#include <cstddef>

#define NND 100000
#define NED 640000

// ---------------------------------------------------------------------------
// degree / dinv
// ---------------------------------------------------------------------------
__global__ __launch_bounds__(256)
void deg_kernel(const int* __restrict__ ei, float* __restrict__ deg) {
    const int e = blockIdx.x * 256 + threadIdx.x;
    if (e < NED) atomicAdd(&deg[ei[NED + e]], 1.0f);   // dst in-degree; adds of 1.0 are exact
}

__global__ __launch_bounds__(256)
void dinv_kernel(float* __restrict__ dinv) {
    const int i = blockIdx.x * 256 + threadIdx.x;
    if (i < NND) dinv[i] = rsqrtf(1.0f + dinv[i]);     // deg + self-loop
}

// ---------------------------------------------------------------------------
// fp32 GEMM, 128x64 block tile, BK=32, 256 threads, 8x4 register tile.
// Fused epilogue: XW = A@B, AGG = dinv^2 * XW (+ bias_out).
// Optional fused A-load: relu(A + bias_in[k])  (layer-2 input).
// ---------------------------------------------------------------------------
template<bool RELU_A, bool HAS_BOUT>
__global__ __launch_bounds__(256)
void gemm_epi(const float* __restrict__ A, const float* __restrict__ B,
              const float* __restrict__ bias_in, const float* __restrict__ bias_out,
              const float* __restrict__ dinv,
              float* __restrict__ XW, float* __restrict__ AGG,
              int M, int N, int K)
{
    constexpr int BM = 128, BN = 64, BK = 32;
    constexpr int ASTR = 132;                 // pad: bank = (4k+m)%32 -> <=2-way (free)
    __shared__ float As[BK][ASTR];            // transposed A tile: As[k][m]
    __shared__ float Bs[BK][BN];              // Bs[k][n]

    const int tid  = threadIdx.x;
    const int tx   = tid & 15;                // col group (0..15) -> 4 cols
    const int ty   = tid >> 4;                // row group (0..15) -> 8 rows
    const int row0 = blockIdx.x * BM;
    const int col0 = blockIdx.y * BN;

    float acc[8][4];
    #pragma unroll
    for (int i = 0; i < 8; ++i)
        #pragma unroll
        for (int j = 0; j < 4; ++j) acc[i][j] = 0.0f;

    const int am  = tid >> 1;                 // A row within tile (0..127)
    const int akb = (tid & 1) * 16;           // A k base (0 or 16)
    const int bn4 = (tid & 15) * 4;
    const int bk  = tid >> 4;                 // 0..15

    for (int kt = 0; kt < K; kt += BK) {
        // ---- stage A (transposed into LDS) ----
        {
            const int row = row0 + am;
            #pragma unroll
            for (int j4 = 0; j4 < 4; ++j4) {
                const int k = akb + j4 * 4;
                float4 v = make_float4(0.f, 0.f, 0.f, 0.f);
                if (row < M) {
                    v = *(const float4*)&A[(size_t)row * K + kt + k];
                    if constexpr (RELU_A) {
                        const float4 bi = *(const float4*)&bias_in[kt + k];
                        v.x = fmaxf(v.x + bi.x, 0.f);
                        v.y = fmaxf(v.y + bi.y, 0.f);
                        v.z = fmaxf(v.z + bi.z, 0.f);
                        v.w = fmaxf(v.w + bi.w, 0.f);
                    }
                }
                As[k + 0][am] = v.x; As[k + 1][am] = v.y;
                As[k + 2][am] = v.z; As[k + 3][am] = v.w;
            }
        }
        // ---- stage B ----
        #pragma unroll
        for (int h = 0; h < 2; ++h) {
            const int k = bk + h * 16;
            *(float4*)&Bs[k][bn4] = *(const float4*)&B[(size_t)(kt + k) * N + col0 + bn4];
        }
        __syncthreads();

        // ---- inner product: 32 FMA per k per thread ----
        #pragma unroll
        for (int k = 0; k < BK; ++k) {
            const float4 a0 = *(const float4*)&As[k][ty * 8];
            const float4 a1 = *(const float4*)&As[k][ty * 8 + 4];
            const float4 b  = *(const float4*)&Bs[k][tx * 4];
            const float av[8] = {a0.x, a0.y, a0.z, a0.w, a1.x, a1.y, a1.z, a1.w};
            const float bv[4] = {b.x, b.y, b.z, b.w};
            #pragma unroll
            for (int i = 0; i < 8; ++i)
                #pragma unroll
                for (int j = 0; j < 4; ++j)
                    acc[i][j] = fmaf(av[i], bv[j], acc[i][j]);
        }
        __syncthreads();
    }

    // ---- epilogue: XW and AGG(self-loop init) ----
    float4 bo = make_float4(0.f, 0.f, 0.f, 0.f);
    if constexpr (HAS_BOUT) bo = *(const float4*)&bias_out[col0 + tx * 4];
    #pragma unroll
    for (int i = 0; i < 8; ++i) {
        const int row = row0 + ty * 8 + i;
        if (row >= M) continue;
        const float d  = dinv[row];
        const float d2 = d * d;
        const float4 v = make_float4(acc[i][0], acc[i][1], acc[i][2], acc[i][3]);
        *(float4*)&XW[(size_t)row * N + col0 + tx * 4] = v;
        const float4 o = make_float4(fmaf(d2, v.x, bo.x), fmaf(d2, v.y, bo.y),
                                     fmaf(d2, v.z, bo.z), fmaf(d2, v.w, bo.w));
        *(float4*)&AGG[(size_t)row * N + col0 + tx * 4] = o;
    }
}

// ---------------------------------------------------------------------------
// edge scatter: agg[dst] += dinv[src]*dinv[dst] * xw[src]
// one thread per (edge, 4 channels)
// ---------------------------------------------------------------------------
__global__ __launch_bounds__(256)
void scatter256(const int* __restrict__ ei, const float* __restrict__ dinv,
                const float* __restrict__ xw, float* __restrict__ agg) {
    const unsigned t = blockIdx.x * 256u + threadIdx.x;
    const int e = t >> 6;                 // 64 chunks of 4 channels
    const int c = (t & 63) << 2;
    const int src = ei[e], dst = ei[NED + e];
    const float w = dinv[src] * dinv[dst];
    const float4 v = *(const float4*)&xw[(size_t)src * 256 + c];
    float* p = &agg[(size_t)dst * 256 + c];
    atomicAdd(p + 0, w * v.x);
    atomicAdd(p + 1, w * v.y);
    atomicAdd(p + 2, w * v.z);
    atomicAdd(p + 3, w * v.w);
}

__global__ __launch_bounds__(256)
void scatter64(const int* __restrict__ ei, const float* __restrict__ dinv,
               const float* __restrict__ xw, float* __restrict__ out) {
    const unsigned t = blockIdx.x * 256u + threadIdx.x;
    const int e = t >> 4;                 // 16 chunks of 4 channels
    const int c = (t & 15) << 2;
    const int src = ei[e], dst = ei[NED + e];
    const float w = dinv[src] * dinv[dst];
    const float4 v = *(const float4*)&xw[(size_t)src * 64 + c];
    float* p = &out[(size_t)dst * 64 + c];
    atomicAdd(p + 0, w * v.x);
    atomicAdd(p + 1, w * v.y);
    atomicAdd(p + 2, w * v.z);
    atomicAdd(p + 3, w * v.w);
}

// ---------------------------------------------------------------------------
extern "C" void kernel_launch(void* const* d_in, const int* in_sizes, int n_in,
                              void* d_out, int out_size, void* d_ws, size_t ws_size,
                              hipStream_t stream)
{
    const float* x  = (const float*)d_in[0];
    const int*   ei = (const int*)d_in[1];   // [2, E]: src row then dst row
    const float* W1 = (const float*)d_in[2];
    const float* b1 = (const float*)d_in[3];
    const float* W2 = (const float*)d_in[4];
    const float* b2 = (const float*)d_in[5];
    float* out = (float*)d_out;

    // workspace layout (bytes):
    //   dinv : [0, 400000)            pad to 400128
    //   xw1  : [400128, +102400000)   (reused as xw2 after layer 1)
    //   agg1 : [102800128, +102400000)
    char* ws   = (char*)d_ws;
    float* dinv = (float*)ws;
    float* xw1  = (float*)(ws + 400128);
    float* agg1 = (float*)(ws + 400128 + 102400000);
    float* xw2  = xw1;                        // xw1 dead after scatter256

    hipMemsetAsync(dinv, 0, NND * sizeof(float), stream);
    deg_kernel<<<(NED + 255) / 256, 256, 0, stream>>>(ei, dinv);
    dinv_kernel<<<(NND + 255) / 256, 256, 0, stream>>>(dinv);

    // layer 1: xw1 = x@W1 ; agg1 = dinv^2*xw1 ; then scatter edges
    gemm_epi<false, false><<<dim3(782, 4), 256, 0, stream>>>(
        x, W1, nullptr, nullptr, dinv, xw1, agg1, NND, 256, 128);
    scatter256<<<(NED * 64) / 256, 256, 0, stream>>>(ei, dinv, xw1, agg1);

    // layer 2: A = relu(agg1 + b1); xw2 = A@W2 ; out = dinv^2*xw2 + b2 ; scatter
    gemm_epi<true, true><<<dim3(782, 1), 256, 0, stream>>>(
        agg1, W2, b1, b2, dinv, xw2, out, NND, 64, 256);
    scatter64<<<(NED * 16) / 256, 256, 0, stream>>>(ei, dinv, xw2, out);
}

// Round 2
// 428.240 us; speedup vs baseline: 6.7619x; 6.7619x over previous
//
#include <hip/hip_runtime.h>
#include <cstdint>
#include <cstddef>

#define NND 100000
#define NED 640000
#define NSCAN_B 98          // ceil(NND/1024)

// ---------------------------------------------------------------------------
// degree count (int) and dinv
// ---------------------------------------------------------------------------
__global__ __launch_bounds__(256)
void deg_kernel(const int* __restrict__ ei, int* __restrict__ cnt) {
    const int e = blockIdx.x * 256 + threadIdx.x;
    if (e < NED) atomicAdd(&cnt[ei[NED + e]], 1);
}

__global__ __launch_bounds__(256)
void dinv_kernel(const int* __restrict__ cnt, float* __restrict__ dinv) {
    const int i = blockIdx.x * 256 + threadIdx.x;
    if (i < NND) dinv[i] = rsqrtf(1.0f + (float)cnt[i]);
}

// ---------------------------------------------------------------------------
// exclusive scan of cnt[NND] -> offs[NND+1]   (3 kernels, 1024 elems/block)
// ---------------------------------------------------------------------------
__global__ __launch_bounds__(256)
void scanA(const int* __restrict__ cnt, int* __restrict__ offs, int* __restrict__ bsum) {
    __shared__ int s[256];
    const int t = threadIdx.x;
    const int base = blockIdx.x * 1024 + t * 4;
    int c0 = (base + 0 < NND) ? cnt[base + 0] : 0;
    int c1 = (base + 1 < NND) ? cnt[base + 1] : 0;
    int c2 = (base + 2 < NND) ? cnt[base + 2] : 0;
    int c3 = (base + 3 < NND) ? cnt[base + 3] : 0;
    const int local = c0 + c1 + c2 + c3;
    s[t] = local;
    __syncthreads();
    for (int off = 1; off < 256; off <<= 1) {       // Hillis-Steele inclusive
        int v = (t >= off) ? s[t - off] : 0;
        __syncthreads();
        s[t] += v;
        __syncthreads();
    }
    const int excl = s[t] - local;
    if (t == 255) bsum[blockIdx.x] = s[255];
    if (base + 0 < NND) offs[base + 0] = excl;
    if (base + 1 < NND) offs[base + 1] = excl + c0;
    if (base + 2 < NND) offs[base + 2] = excl + c0 + c1;
    if (base + 3 < NND) offs[base + 3] = excl + c0 + c1 + c2;
}

__global__ __launch_bounds__(64)
void scanB(int* __restrict__ bsum, int* __restrict__ offs) {
    if (threadIdx.x == 0) {
        int run = 0;
        for (int b = 0; b < NSCAN_B; ++b) { int v = bsum[b]; bsum[b] = run; run += v; }
        offs[NND] = NED;
    }
}

// offs[i] += bsum[block]; cursor (=cnt reused) initialized to final offset
__global__ __launch_bounds__(256)
void scanC(int* __restrict__ offs, const int* __restrict__ bsum, int* __restrict__ cursor) {
    const int i = blockIdx.x * 256 + threadIdx.x;
    if (i < NND) {
        const int v = offs[i] + bsum[i >> 10];
        offs[i] = v;
        cursor[i] = v;
    }
}

// fill CSR: srcS[pos] = src, sorted by dst
__global__ __launch_bounds__(256)
void fill_kernel(const int* __restrict__ ei, int* __restrict__ cursor,
                 int* __restrict__ srcS) {
    const int e = blockIdx.x * 256 + threadIdx.x;
    if (e < NED) {
        const int src = ei[e], dst = ei[NED + e];
        const int p = atomicAdd(&cursor[dst], 1);
        srcS[p] = src;
    }
}

// ---------------------------------------------------------------------------
// fp32 GEMM, 128x64 block tile, BK=32, 256 threads, 8x4 register tile.
// Fused epilogue: XW = A@B, AGG = dinv^2 * XW (+ bias_out).
// Optional fused A-load: relu(A + bias_in[k])  (layer-2 input).
// ---------------------------------------------------------------------------
template<bool RELU_A, bool HAS_BOUT>
__global__ __launch_bounds__(256)
void gemm_epi(const float* __restrict__ A, const float* __restrict__ B,
              const float* __restrict__ bias_in, const float* __restrict__ bias_out,
              const float* __restrict__ dinv,
              float* __restrict__ XW, float* __restrict__ AGG,
              int M, int N, int K)
{
    constexpr int BM = 128, BN = 64, BK = 32;
    constexpr int ASTR = 132;
    __shared__ float As[BK][ASTR];            // transposed A tile: As[k][m]
    __shared__ float Bs[BK][BN];

    const int tid  = threadIdx.x;
    const int tx   = tid & 15;
    const int ty   = tid >> 4;
    const int row0 = blockIdx.x * BM;
    const int col0 = blockIdx.y * BN;

    float acc[8][4];
    #pragma unroll
    for (int i = 0; i < 8; ++i)
        #pragma unroll
        for (int j = 0; j < 4; ++j) acc[i][j] = 0.0f;

    const int am  = tid >> 1;
    const int akb = (tid & 1) * 16;
    const int bn4 = (tid & 15) * 4;
    const int bk  = tid >> 4;

    for (int kt = 0; kt < K; kt += BK) {
        {
            const int row = row0 + am;
            #pragma unroll
            for (int j4 = 0; j4 < 4; ++j4) {
                const int k = akb + j4 * 4;
                float4 v = make_float4(0.f, 0.f, 0.f, 0.f);
                if (row < M) {
                    v = *(const float4*)&A[(size_t)row * K + kt + k];
                    if constexpr (RELU_A) {
                        const float4 bi = *(const float4*)&bias_in[kt + k];
                        v.x = fmaxf(v.x + bi.x, 0.f);
                        v.y = fmaxf(v.y + bi.y, 0.f);
                        v.z = fmaxf(v.z + bi.z, 0.f);
                        v.w = fmaxf(v.w + bi.w, 0.f);
                    }
                }
                As[k + 0][am] = v.x; As[k + 1][am] = v.y;
                As[k + 2][am] = v.z; As[k + 3][am] = v.w;
            }
        }
        #pragma unroll
        for (int h = 0; h < 2; ++h) {
            const int k = bk + h * 16;
            *(float4*)&Bs[k][bn4] = *(const float4*)&B[(size_t)(kt + k) * N + col0 + bn4];
        }
        __syncthreads();

        #pragma unroll
        for (int k = 0; k < BK; ++k) {
            const float4 a0 = *(const float4*)&As[k][ty * 8];
            const float4 a1 = *(const float4*)&As[k][ty * 8 + 4];
            const float4 b  = *(const float4*)&Bs[k][tx * 4];
            const float av[8] = {a0.x, a0.y, a0.z, a0.w, a1.x, a1.y, a1.z, a1.w};
            const float bv[4] = {b.x, b.y, b.z, b.w};
            #pragma unroll
            for (int i = 0; i < 8; ++i)
                #pragma unroll
                for (int j = 0; j < 4; ++j)
                    acc[i][j] = fmaf(av[i], bv[j], acc[i][j]);
        }
        __syncthreads();
    }

    float4 bo = make_float4(0.f, 0.f, 0.f, 0.f);
    if constexpr (HAS_BOUT) bo = *(const float4*)&bias_out[col0 + tx * 4];
    #pragma unroll
    for (int i = 0; i < 8; ++i) {
        const int row = row0 + ty * 8 + i;
        if (row >= M) continue;
        const float d  = dinv[row];
        const float d2 = d * d;
        const float4 v = make_float4(acc[i][0], acc[i][1], acc[i][2], acc[i][3]);
        *(float4*)&XW[(size_t)row * N + col0 + tx * 4] = v;
        const float4 o = make_float4(fmaf(d2, v.x, bo.x), fmaf(d2, v.y, bo.y),
                                     fmaf(d2, v.z, bo.z), fmaf(d2, v.w, bo.w));
        *(float4*)&AGG[(size_t)row * N + col0 + tx * 4] = o;
    }
}

// ---------------------------------------------------------------------------
// CSR gather: one wave per dst node. agg[dst] += sum_e dinv[src]*dinv[dst]*xw[src]
// agg already holds the self-loop term (+bias for layer 2).
// ---------------------------------------------------------------------------
__global__ __launch_bounds__(256)
void gather256(const int* __restrict__ offs, const int* __restrict__ srcS,
               const float* __restrict__ dinv,
               const float* __restrict__ xw, float* __restrict__ agg) {
    const int d    = (blockIdx.x * 256 + threadIdx.x) >> 6;
    const int lane = threadIdx.x & 63;
    if (d >= NND) return;
    const int beg = offs[d], end = offs[d + 1];
    const float dd = dinv[d];
    float* p = &agg[(size_t)d * 256 + lane * 4];
    float4 acc = *(const float4*)p;                     // self-loop init
    for (int e = beg; e < end; ++e) {
        const int   src = srcS[e];
        const float wt  = dinv[src] * dd;
        const float4 v  = *(const float4*)&xw[(size_t)src * 256 + lane * 4];
        acc.x = fmaf(wt, v.x, acc.x);
        acc.y = fmaf(wt, v.y, acc.y);
        acc.z = fmaf(wt, v.z, acc.z);
        acc.w = fmaf(wt, v.w, acc.w);
    }
    *(float4*)p = acc;
}

__global__ __launch_bounds__(256)
void gather64(const int* __restrict__ offs, const int* __restrict__ srcS,
              const float* __restrict__ dinv,
              const float* __restrict__ xw, float* __restrict__ out) {
    const int d    = (blockIdx.x * 256 + threadIdx.x) >> 6;
    const int lane = threadIdx.x & 63;
    if (d >= NND) return;
    const int beg = offs[d], end = offs[d + 1];
    const float dd = dinv[d];
    float* p = &out[(size_t)d * 64 + lane];
    float acc = *p;                                     // self-loop + bias init
    for (int e = beg; e < end; ++e) {
        const int   src = srcS[e];
        const float wt  = dinv[src] * dd;
        acc = fmaf(wt, xw[(size_t)src * 64 + lane], acc);
    }
    *p = acc;
}

// ---------------------------------------------------------------------------
extern "C" void kernel_launch(void* const* d_in, const int* in_sizes, int n_in,
                              void* d_out, int out_size, void* d_ws, size_t ws_size,
                              hipStream_t stream)
{
    const float* x  = (const float*)d_in[0];
    const int*   ei = (const int*)d_in[1];   // [2, E]: src row then dst row
    const float* W1 = (const float*)d_in[2];
    const float* b1 = (const float*)d_in[3];
    const float* W2 = (const float*)d_in[4];
    const float* b2 = (const float*)d_in[5];
    float* out = (float*)d_out;

    // workspace layout (bytes):
    char* ws = (char*)d_ws;
    float* dinv  = (float*)(ws + 0);           // 400,000  -> pad 400,128
    int*   cnt   = (int*)  (ws + 400128);      // 400,000  -> pad 800,256   (reused as cursor)
    int*   offs  = (int*)  (ws + 800256);      // 400,004  -> pad 1,200,384
    int*   bsum  = (int*)  (ws + 1200384);     // 392      -> pad 1,201,408
    int*   srcS  = (int*)  (ws + 1201408);     // 2,560,000 -> pad 3,761,408
    float* xw1   = (float*)(ws + 3761408);     // 102,400,000
    float* agg1  = (float*)(ws + 106161408);   // 102,400,000 (end 208,561,408)
    float* xw2   = xw1;                        // xw1 dead after gather256

    // ---- CSR build ----
    hipMemsetAsync(cnt, 0, NND * sizeof(int), stream);
    deg_kernel<<<(NED + 255) / 256, 256, 0, stream>>>(ei, cnt);
    dinv_kernel<<<(NND + 255) / 256, 256, 0, stream>>>(cnt, dinv);
    scanA<<<NSCAN_B, 256, 0, stream>>>(cnt, offs, bsum);
    scanB<<<1, 64, 0, stream>>>(bsum, offs);
    scanC<<<(NND + 255) / 256, 256, 0, stream>>>(offs, bsum, cnt);
    fill_kernel<<<(NED + 255) / 256, 256, 0, stream>>>(ei, cnt, srcS);

    // ---- layer 1 ----
    gemm_epi<false, false><<<dim3(782, 4), 256, 0, stream>>>(
        x, W1, nullptr, nullptr, dinv, xw1, agg1, NND, 256, 128);
    gather256<<<(NND * 64 + 255) / 256, 256, 0, stream>>>(offs, srcS, dinv, xw1, agg1);

    // ---- layer 2 ----
    gemm_epi<true, true><<<dim3(782, 1), 256, 0, stream>>>(
        agg1, W2, b1, b2, dinv, xw2, out, NND, 64, 256);
    gather64<<<(NND * 64 + 255) / 256, 256, 0, stream>>>(offs, srcS, dinv, xw2, out);
}

// Round 3
// 381.764 us; speedup vs baseline: 7.5851x; 1.1217x over previous
//
#include <hip/hip_runtime.h>
#include <cstdint>
#include <cstddef>

#define NND 100000
#define NED 640000
#define NSCAN_B 98          // ceil(NND/1024)

// ---------------------------------------------------------------------------
// degree count (int) and dinv
// ---------------------------------------------------------------------------
__global__ __launch_bounds__(256)
void deg_kernel(const int* __restrict__ ei, int* __restrict__ cnt) {
    const int e = blockIdx.x * 256 + threadIdx.x;
    if (e < NED) atomicAdd(&cnt[ei[NED + e]], 1);
}

__global__ __launch_bounds__(256)
void dinv_kernel(const int* __restrict__ cnt, float* __restrict__ dinv) {
    const int i = blockIdx.x * 256 + threadIdx.x;
    if (i < NND) dinv[i] = rsqrtf(1.0f + (float)cnt[i]);
}

// ---------------------------------------------------------------------------
// exclusive scan of cnt[NND] -> offs[NND+1]
// ---------------------------------------------------------------------------
__global__ __launch_bounds__(256)
void scanA(const int* __restrict__ cnt, int* __restrict__ offs, int* __restrict__ bsum) {
    __shared__ int s[256];
    const int t = threadIdx.x;
    const int base = blockIdx.x * 1024 + t * 4;
    int c0 = (base + 0 < NND) ? cnt[base + 0] : 0;
    int c1 = (base + 1 < NND) ? cnt[base + 1] : 0;
    int c2 = (base + 2 < NND) ? cnt[base + 2] : 0;
    int c3 = (base + 3 < NND) ? cnt[base + 3] : 0;
    const int local = c0 + c1 + c2 + c3;
    s[t] = local;
    __syncthreads();
    for (int off = 1; off < 256; off <<= 1) {
        int v = (t >= off) ? s[t - off] : 0;
        __syncthreads();
        s[t] += v;
        __syncthreads();
    }
    const int excl = s[t] - local;
    if (t == 255) bsum[blockIdx.x] = s[255];
    if (base + 0 < NND) offs[base + 0] = excl;
    if (base + 1 < NND) offs[base + 1] = excl + c0;
    if (base + 2 < NND) offs[base + 2] = excl + c0 + c1;
    if (base + 3 < NND) offs[base + 3] = excl + c0 + c1 + c2;
}

__global__ __launch_bounds__(64)
void scanB(int* __restrict__ bsum, int* __restrict__ offs) {
    if (threadIdx.x == 0) {
        int run = 0;
        for (int b = 0; b < NSCAN_B; ++b) { int v = bsum[b]; bsum[b] = run; run += v; }
        offs[NND] = NED;
    }
}

__global__ __launch_bounds__(256)
void scanC(int* __restrict__ offs, const int* __restrict__ bsum, int* __restrict__ cursor) {
    const int i = blockIdx.x * 256 + threadIdx.x;
    if (i < NND) {
        const int v = offs[i] + bsum[i >> 10];
        offs[i] = v;
        cursor[i] = v;
    }
}

__global__ __launch_bounds__(256)
void fill_kernel(const int* __restrict__ ei, int* __restrict__ cursor,
                 int* __restrict__ srcS) {
    const int e = blockIdx.x * 256 + threadIdx.x;
    if (e < NED) {
        const int src = ei[e], dst = ei[NED + e];
        const int p = atomicAdd(&cursor[dst], 1);
        srcS[p] = src;
    }
}

// ---------------------------------------------------------------------------
// fp32 GEMM, 128x64 block tile, BK=32, 256 threads, 8x4 register tile.
// RELU_OUT: XW = relu(A@B + bias)           (layer-1 h)
// !RELU_OUT: XW = A@B ; AGG = dinv^2*XW+bias (layer-2 xw2 + out-init)
// ---------------------------------------------------------------------------
template<bool RELU_OUT>
__global__ __launch_bounds__(256)
void gemm_epi(const float* __restrict__ A, const float* __restrict__ B,
              const float* __restrict__ bias, const float* __restrict__ dinv,
              float* __restrict__ XW, float* __restrict__ AGG,
              int M, int N, int K)
{
    constexpr int BM = 128, BN = 64, BK = 32;
    constexpr int ASTR = 132;
    __shared__ float As[BK][ASTR];            // transposed A tile: As[k][m]
    __shared__ float Bs[BK][BN];

    const int tid  = threadIdx.x;
    const int tx   = tid & 15;
    const int ty   = tid >> 4;
    const int row0 = blockIdx.x * BM;
    const int col0 = blockIdx.y * BN;

    float acc[8][4];
    #pragma unroll
    for (int i = 0; i < 8; ++i)
        #pragma unroll
        for (int j = 0; j < 4; ++j) acc[i][j] = 0.0f;

    const int am  = tid >> 1;
    const int akb = (tid & 1) * 16;
    const int bn4 = (tid & 15) * 4;
    const int bk  = tid >> 4;

    for (int kt = 0; kt < K; kt += BK) {
        {
            const int row = row0 + am;
            #pragma unroll
            for (int j4 = 0; j4 < 4; ++j4) {
                const int k = akb + j4 * 4;
                float4 v = make_float4(0.f, 0.f, 0.f, 0.f);
                if (row < M) v = *(const float4*)&A[(size_t)row * K + kt + k];
                As[k + 0][am] = v.x; As[k + 1][am] = v.y;
                As[k + 2][am] = v.z; As[k + 3][am] = v.w;
            }
        }
        #pragma unroll
        for (int h = 0; h < 2; ++h) {
            const int k = bk + h * 16;
            *(float4*)&Bs[k][bn4] = *(const float4*)&B[(size_t)(kt + k) * N + col0 + bn4];
        }
        __syncthreads();

        #pragma unroll
        for (int k = 0; k < BK; ++k) {
            const float4 a0 = *(const float4*)&As[k][ty * 8];
            const float4 a1 = *(const float4*)&As[k][ty * 8 + 4];
            const float4 b  = *(const float4*)&Bs[k][tx * 4];
            const float av[8] = {a0.x, a0.y, a0.z, a0.w, a1.x, a1.y, a1.z, a1.w};
            const float bv[4] = {b.x, b.y, b.z, b.w};
            #pragma unroll
            for (int i = 0; i < 8; ++i)
                #pragma unroll
                for (int j = 0; j < 4; ++j)
                    acc[i][j] = fmaf(av[i], bv[j], acc[i][j]);
        }
        __syncthreads();
    }

    const float4 bo = *(const float4*)&bias[col0 + tx * 4];
    #pragma unroll
    for (int i = 0; i < 8; ++i) {
        const int row = row0 + ty * 8 + i;
        if (row >= M) continue;
        float4 v = make_float4(acc[i][0], acc[i][1], acc[i][2], acc[i][3]);
        if constexpr (RELU_OUT) {
            v.x = fmaxf(v.x + bo.x, 0.f);
            v.y = fmaxf(v.y + bo.y, 0.f);
            v.z = fmaxf(v.z + bo.z, 0.f);
            v.w = fmaxf(v.w + bo.w, 0.f);
            *(float4*)&XW[(size_t)row * N + col0 + tx * 4] = v;
        } else {
            *(float4*)&XW[(size_t)row * N + col0 + tx * 4] = v;
            const float d  = dinv[row];
            const float d2 = d * d;
            const float4 o = make_float4(fmaf(d2, v.x, bo.x), fmaf(d2, v.y, bo.y),
                                         fmaf(d2, v.z, bo.z), fmaf(d2, v.w, bo.w));
            *(float4*)&AGG[(size_t)row * N + col0 + tx * 4] = o;
        }
    }
}

// ---------------------------------------------------------------------------
// CSR gathers: one wave per dst node, single-owner non-atomic writes.
// gather128: z[d] = dinv[d]^2 * x[d] + sum_e dinv[src]*dinv[d] * x[src]
// ---------------------------------------------------------------------------
__global__ __launch_bounds__(256)
void gather128(const int* __restrict__ offs, const int* __restrict__ srcS,
               const float* __restrict__ dinv,
               const float* __restrict__ x, float* __restrict__ z) {
    const int d    = (blockIdx.x * 256 + threadIdx.x) >> 6;
    const int lane = threadIdx.x & 63;
    if (d >= NND) return;
    const int beg = offs[d], end = offs[d + 1];
    const float dd = dinv[d];
    const float2* __restrict__ x2 = (const float2*)x;
    float2 acc = x2[(size_t)d * 64 + lane];
    acc.x *= dd * dd;  acc.y *= dd * dd;               // self-loop
    for (int e = beg; e < end; ++e) {
        const int   src = srcS[e];
        const float wt  = dinv[src] * dd;
        const float2 v  = x2[(size_t)src * 64 + lane];
        acc.x = fmaf(wt, v.x, acc.x);
        acc.y = fmaf(wt, v.y, acc.y);
    }
    *(float2*)&z[(size_t)d * 128 + lane * 2] = acc;
}

// out[d] += sum_e dinv[src]*dinv[d] * xw[src]   (out pre-init by gemm2 epilogue)
__global__ __launch_bounds__(256)
void gather64(const int* __restrict__ offs, const int* __restrict__ srcS,
              const float* __restrict__ dinv,
              const float* __restrict__ xw, float* __restrict__ out) {
    const int d    = (blockIdx.x * 256 + threadIdx.x) >> 6;
    const int lane = threadIdx.x & 63;
    if (d >= NND) return;
    const int beg = offs[d], end = offs[d + 1];
    const float dd = dinv[d];
    float* p = &out[(size_t)d * 64 + lane];
    float acc = *p;
    for (int e = beg; e < end; ++e) {
        const int   src = srcS[e];
        const float wt  = dinv[src] * dd;
        acc = fmaf(wt, xw[(size_t)src * 64 + lane], acc);
    }
    *p = acc;
}

// ---------------------------------------------------------------------------
extern "C" void kernel_launch(void* const* d_in, const int* in_sizes, int n_in,
                              void* d_out, int out_size, void* d_ws, size_t ws_size,
                              hipStream_t stream)
{
    const float* x  = (const float*)d_in[0];
    const int*   ei = (const int*)d_in[1];   // [2, E]: src row then dst row
    const float* W1 = (const float*)d_in[2];
    const float* b1 = (const float*)d_in[3];
    const float* W2 = (const float*)d_in[4];
    const float* b2 = (const float*)d_in[5];
    float* out = (float*)d_out;

    // workspace layout (bytes):
    char* ws = (char*)d_ws;
    float* dinv  = (float*)(ws + 0);           // 400,000   -> pad 400,128
    int*   cnt   = (int*)  (ws + 400128);      // 400,000   -> pad 800,256  (reused as cursor)
    int*   offs  = (int*)  (ws + 800256);      // 400,004   -> pad 1,200,384
    int*   bsum  = (int*)  (ws + 1200384);     // 392       -> pad 1,201,408
    int*   srcS  = (int*)  (ws + 1201408);     // 2,560,000 -> pad 3,761,408
    float* z     = (float*)(ws + 3761408);     // 51,200,000  (Ā·x, 128-dim)
    float* h     = (float*)(ws + 54961408);    // 102,400,000 (relu(zW1+b1))
    float* xw2   = (float*)(ws + 157361408);   // 25,600,000  (end 182,961,408)

    // ---- CSR build ----
    hipMemsetAsync(cnt, 0, NND * sizeof(int), stream);
    deg_kernel<<<(NED + 255) / 256, 256, 0, stream>>>(ei, cnt);
    dinv_kernel<<<(NND + 255) / 256, 256, 0, stream>>>(cnt, dinv);
    scanA<<<NSCAN_B, 256, 0, stream>>>(cnt, offs, bsum);
    scanB<<<1, 64, 0, stream>>>(bsum, offs);
    scanC<<<(NND + 255) / 256, 256, 0, stream>>>(offs, bsum, cnt);
    fill_kernel<<<(NED + 255) / 256, 256, 0, stream>>>(ei, cnt, srcS);

    // ---- layer 1:  z = Ā·x  (128-dim gather)  then  h = relu(z@W1 + b1) ----
    gather128<<<(NND * 64 + 255) / 256, 256, 0, stream>>>(offs, srcS, dinv, x, z);
    gemm_epi<true><<<dim3(782, 4), 256, 0, stream>>>(
        z, W1, b1, nullptr, h, nullptr, NND, 256, 128);

    // ---- layer 2:  xw2 = h@W2 ; out = dinv^2*xw2 + b2 ; then gather edges ----
    gemm_epi<false><<<dim3(782, 1), 256, 0, stream>>>(
        h, W2, b2, dinv, xw2, out, NND, 64, 256);
    gather64<<<(NND * 64 + 255) / 256, 256, 0, stream>>>(offs, srcS, dinv, xw2, out);
}

// Round 4
// 281.139 us; speedup vs baseline: 10.3000x; 1.3579x over previous
//
#include <hip/hip_runtime.h>
#include <cstdint>
#include <cstddef>

#define NND 100000
#define NED 640000
#define NSCAN_B 98          // ceil(NND/1024)

typedef unsigned int u32;
typedef unsigned short u16;
typedef __attribute__((ext_vector_type(8))) short bf16x8;
typedef __attribute__((ext_vector_type(4))) float f32x4;

// ---------------------------------------------------------------------------
// helpers: fp32 <-> bf16 (RNE), async global->LDS 16B
// ---------------------------------------------------------------------------
__device__ __forceinline__ u16 f2b(float f) {
    u32 u = __float_as_uint(f);
    return (u16)((u + 0x7fffu + ((u >> 16) & 1u)) >> 16);
}
__device__ __forceinline__ float b2f(u16 b) {
    return __uint_as_float(((u32)b) << 16);
}
__device__ __forceinline__ u32 pack2(float a, float b) {
    return (u32)f2b(a) | ((u32)f2b(b) << 16);
}
__device__ __forceinline__ void gload16(u16* lds, const u16* g) {
    __builtin_amdgcn_global_load_lds(
        (const __attribute__((address_space(1))) u32*)g,
        (__attribute__((address_space(3))) u32*)lds,
        16, 0, 0);
}

// ---------------------------------------------------------------------------
// degree count (int) and dinv
// ---------------------------------------------------------------------------
__global__ __launch_bounds__(256)
void deg_kernel(const int* __restrict__ ei, int* __restrict__ cnt) {
    const int e = blockIdx.x * 256 + threadIdx.x;
    if (e < NED) atomicAdd(&cnt[ei[NED + e]], 1);
}

__global__ __launch_bounds__(256)
void dinv_kernel(const int* __restrict__ cnt, float* __restrict__ dinv) {
    const int i = blockIdx.x * 256 + threadIdx.x;
    if (i < NND) dinv[i] = rsqrtf(1.0f + (float)cnt[i]);
}

// ---------------------------------------------------------------------------
// exclusive scan of cnt[NND] -> offs[NND+1]
// ---------------------------------------------------------------------------
__global__ __launch_bounds__(256)
void scanA(const int* __restrict__ cnt, int* __restrict__ offs, int* __restrict__ bsum) {
    __shared__ int s[256];
    const int t = threadIdx.x;
    const int base = blockIdx.x * 1024 + t * 4;
    int c0 = (base + 0 < NND) ? cnt[base + 0] : 0;
    int c1 = (base + 1 < NND) ? cnt[base + 1] : 0;
    int c2 = (base + 2 < NND) ? cnt[base + 2] : 0;
    int c3 = (base + 3 < NND) ? cnt[base + 3] : 0;
    const int local = c0 + c1 + c2 + c3;
    s[t] = local;
    __syncthreads();
    for (int off = 1; off < 256; off <<= 1) {
        int v = (t >= off) ? s[t - off] : 0;
        __syncthreads();
        s[t] += v;
        __syncthreads();
    }
    const int excl = s[t] - local;
    if (t == 255) bsum[blockIdx.x] = s[255];
    if (base + 0 < NND) offs[base + 0] = excl;
    if (base + 1 < NND) offs[base + 1] = excl + c0;
    if (base + 2 < NND) offs[base + 2] = excl + c0 + c1;
    if (base + 3 < NND) offs[base + 3] = excl + c0 + c1 + c2;
}

__global__ __launch_bounds__(64)
void scanB(int* __restrict__ bsum, int* __restrict__ offs) {
    if (threadIdx.x == 0) {
        int run = 0;
        for (int b = 0; b < NSCAN_B; ++b) { int v = bsum[b]; bsum[b] = run; run += v; }
        offs[NND] = NED;
    }
}

__global__ __launch_bounds__(256)
void scanC(int* __restrict__ offs, const int* __restrict__ bsum, int* __restrict__ cursor) {
    const int i = blockIdx.x * 256 + threadIdx.x;
    if (i < NND) {
        const int v = offs[i] + bsum[i >> 10];
        offs[i] = v;
        cursor[i] = v;
    }
}

__global__ __launch_bounds__(256)
void fill_kernel(const int* __restrict__ ei, int* __restrict__ cursor,
                 int* __restrict__ srcS) {
    const int e = blockIdx.x * 256 + threadIdx.x;
    if (e < NED) {
        const int src = ei[e], dst = ei[NED + e];
        const int p = atomicAdd(&cursor[dst], 1);
        srcS[p] = src;
    }
}

// ---------------------------------------------------------------------------
// conversions: x -> bf16 ; W1,W2 -> transposed bf16 (Wt[n][k])
// ---------------------------------------------------------------------------
__global__ __launch_bounds__(256)
void cvt_x_kernel(const float* __restrict__ x, u32* __restrict__ xb) {
    const int i = blockIdx.x * 256 + threadIdx.x;      // exactly 3,200,000 threads
    const float4 v = *(const float4*)&x[(size_t)i * 4];
    xb[(size_t)i * 2 + 0] = pack2(v.x, v.y);
    xb[(size_t)i * 2 + 1] = pack2(v.z, v.w);
}

__global__ __launch_bounds__(256)
void cvt_w_kernel(const float* __restrict__ W1, const float* __restrict__ W2,
                  u16* __restrict__ W1t, u16* __restrict__ W2t) {
    const int i = blockIdx.x * 256 + threadIdx.x;      // 49152 threads
    if (i < 128 * 256) {
        const int k = i >> 8, n = i & 255;
        W1t[n * 128 + k] = f2b(W1[i]);
    } else {
        const int j = i - 128 * 256;                   // j < 256*64
        const int k = j >> 6, n = j & 63;
        W2t[n * 256 + k] = f2b(W2[j]);
    }
}

// ---------------------------------------------------------------------------
// CSR gather (bf16 in, bf16 out):  z[d] = dinv[d]^2*x[d] + sum dinv[s]*dinv[d]*x[s]
// one wave per node, lane owns 2 channels (u32 = 2 bf16).
// ---------------------------------------------------------------------------
__global__ __launch_bounds__(256)
void gather128b(const int* __restrict__ offs, const int* __restrict__ srcS,
                const float* __restrict__ dinv,
                const u32* __restrict__ xb, u32* __restrict__ zb) {
    const int d    = (blockIdx.x * 256 + threadIdx.x) >> 6;
    const int lane = threadIdx.x & 63;
    if (d >= NND) return;
    const int beg = offs[d], end = offs[d + 1];
    const float dd = dinv[d];
    const u32 s = xb[(size_t)d * 64 + lane];
    float ax = b2f((u16)s) * dd * dd;
    float ay = b2f((u16)(s >> 16)) * dd * dd;
    for (int e = beg; e < end; ++e) {
        const int   src = srcS[e];
        const float wt  = dinv[src] * dd;
        const u32   v   = xb[(size_t)src * 64 + lane];
        ax = fmaf(wt, b2f((u16)v), ax);
        ay = fmaf(wt, b2f((u16)(v >> 16)), ay);
    }
    zb[(size_t)d * 64 + lane] = pack2(ax, ay);
}

// out[d] += sum dinv[s]*dinv[d]*xw2[s]   (out pre-init by gemm2 epilogue; xw2 bf16)
__global__ __launch_bounds__(256)
void gather64b(const int* __restrict__ offs, const int* __restrict__ srcS,
               const float* __restrict__ dinv,
               const u16* __restrict__ xwb, float* __restrict__ out) {
    const int d    = (blockIdx.x * 256 + threadIdx.x) >> 6;
    const int lane = threadIdx.x & 63;
    if (d >= NND) return;
    const int beg = offs[d], end = offs[d + 1];
    const float dd = dinv[d];
    float* p = &out[(size_t)d * 64 + lane];
    float acc = *p;
    for (int e = beg; e < end; ++e) {
        const int   src = srcS[e];
        const float wt  = dinv[src] * dd;
        acc = fmaf(wt, b2f(xwb[(size_t)src * 64 + lane]), acc);
    }
    *p = acc;
}

// ---------------------------------------------------------------------------
// bf16 MFMA GEMM: C = A[M][K] @ Bt[N][K]^T, 4 waves, 64x64 per wave, BK=32.
// A, Bt bf16; acc fp32 via mfma_f32_16x16x32_bf16.
// EPI 0: O1(bf16) = relu(acc + bias[col])                       (layer-1 h)
// EPI 1: O1(bf16) = acc ; O2(fp32) = dinv[row]^2*acc + bias[col] (xw2 + out-init)
// Fragment layouts: A/B lane holds idx=lane&15 (m or n), k=(lane>>4)*8+j;
// C/D col=lane&15, row=(lane>>4)*4+reg  [m89-verified].
// ---------------------------------------------------------------------------
template<int BM, int BN, int WM, int WN, int EPI>
__global__ __launch_bounds__(256)
void gemm_mfma(const u16* __restrict__ A, const u16* __restrict__ Bt,
               const float* __restrict__ bias, const float* __restrict__ dinv,
               void* __restrict__ O1, float* __restrict__ O2,
               int M, int N, int K)
{
    __shared__ __align__(16) u16 As[BM * 32];
    __shared__ __align__(16) u16 Bs[BN * 32];
    const int tid  = threadIdx.x;
    const int lane = tid & 63;
    const int wid  = tid >> 6;
    const int wm   = wid % WM;
    const int wn   = wid / WM;
    const int row0 = blockIdx.x * BM;
    const int col0 = blockIdx.y * BN;
    const int wrow0 = wm * 64, wcol0 = wn * 64;

    f32x4 acc[4][4];
    #pragma unroll
    for (int i = 0; i < 4; ++i)
        #pragma unroll
        for (int j = 0; j < 4; ++j) acc[i][j] = (f32x4){0.f, 0.f, 0.f, 0.f};

    const int lr = lane >> 2;          // 0..15: row within 16-row load chunk
    const int lk = (lane & 3) * 8;     // k-element offset (16B granule)

    for (int kt = 0; kt < K; kt += 32) {
        #pragma unroll
        for (int j = 0; j < BM / 64; ++j) {
            const int li = wid * (BM / 64) + j;            // 16 rows per load
            const int r  = li * 16 + lr;
            const int rg = (row0 + r < M) ? (row0 + r) : (M - 1);
            gload16(&As[li * 512], &A[(size_t)rg * K + kt + lk]);
        }
        #pragma unroll
        for (int j = 0; j < BN / 64; ++j) {
            const int li = wid * (BN / 64) + j;
            const int n  = li * 16 + lr;
            gload16(&Bs[li * 512], &Bt[(size_t)(col0 + n) * K + kt + lk]);
        }
        __syncthreads();

        bf16x8 af[4], bfr[4];
        #pragma unroll
        for (int mi = 0; mi < 4; ++mi)
            af[mi] = *(const bf16x8*)&As[(wrow0 + mi * 16 + (lane & 15)) * 32 + (lane >> 4) * 8];
        #pragma unroll
        for (int ni = 0; ni < 4; ++ni)
            bfr[ni] = *(const bf16x8*)&Bs[(wcol0 + ni * 16 + (lane & 15)) * 32 + (lane >> 4) * 8];
        #pragma unroll
        for (int mi = 0; mi < 4; ++mi)
            #pragma unroll
            for (int ni = 0; ni < 4; ++ni)
                acc[mi][ni] = __builtin_amdgcn_mfma_f32_16x16x32_bf16(
                    af[mi], bfr[ni], acc[mi][ni], 0, 0, 0);
        __syncthreads();
    }

    const int rb = (lane >> 4) * 4;
    const int cl = lane & 15;
    #pragma unroll
    for (int mi = 0; mi < 4; ++mi) {
        #pragma unroll
        for (int r = 0; r < 4; ++r) {
            const int row = row0 + wrow0 + mi * 16 + rb + r;
            if (row >= M) continue;
            #pragma unroll
            for (int ni = 0; ni < 4; ++ni) {
                const int col = col0 + wcol0 + ni * 16 + cl;
                const float v = acc[mi][ni][r];
                if constexpr (EPI == 0) {
                    ((u16*)O1)[(size_t)row * N + col] = f2b(fmaxf(v + bias[col], 0.f));
                } else {
                    ((u16*)O1)[(size_t)row * N + col] = f2b(v);
                    const float dd = dinv[row];
                    O2[(size_t)row * N + col] = fmaf(dd * dd, v, bias[col]);
                }
            }
        }
    }
}

// ---------------------------------------------------------------------------
extern "C" void kernel_launch(void* const* d_in, const int* in_sizes, int n_in,
                              void* d_out, int out_size, void* d_ws, size_t ws_size,
                              hipStream_t stream)
{
    const float* x  = (const float*)d_in[0];
    const int*   ei = (const int*)d_in[1];   // [2, E]: src row then dst row
    const float* W1 = (const float*)d_in[2];
    const float* b1 = (const float*)d_in[3];
    const float* W2 = (const float*)d_in[4];
    const float* b2 = (const float*)d_in[5];
    float* out = (float*)d_out;

    // workspace layout (bytes, all 128-aligned):
    char* ws = (char*)d_ws;
    float* dinv = (float*)(ws + 0);            //    400,000 -> 400,128
    int*   cnt  = (int*)  (ws + 400128);       //    400,000 -> 800,128 (reused as cursor)
    int*   offs = (int*)  (ws + 800128);       //    400,004 -> 1,200,256
    int*   bsum = (int*)  (ws + 1200256);      //        512 -> 1,200,768
    int*   srcS = (int*)  (ws + 1200768);      //  2,560,000 -> 3,760,768
    u32*   xb   = (u32*)  (ws + 3760768);      // 25,600,000 -> 29,360,768  (x bf16)
    u32*   zb   = (u32*)  (ws + 29360768);     // 25,600,000 -> 54,960,768  (Ax bf16)
    u16*   hb   = (u16*)  (ws + 54960768);     // 51,200,000 -> 106,160,768 (h bf16)
    u16*   W1t  = (u16*)  (ws + 106160768);    //     65,536 -> 106,226,304
    u16*   W2t  = (u16*)  (ws + 106226304);    //     32,768 -> 106,259,072
    u16*   xwb  = (u16*)  (ws + 106259072);    // 12,800,000 -> 119,059,072 (xw2 bf16)

    // ---- CSR build + dinv ----
    hipMemsetAsync(cnt, 0, NND * sizeof(int), stream);
    deg_kernel<<<(NED + 255) / 256, 256, 0, stream>>>(ei, cnt);
    dinv_kernel<<<(NND + 255) / 256, 256, 0, stream>>>(cnt, dinv);
    scanA<<<NSCAN_B, 256, 0, stream>>>(cnt, offs, bsum);
    scanB<<<1, 64, 0, stream>>>(bsum, offs);
    scanC<<<(NND + 255) / 256, 256, 0, stream>>>(offs, bsum, cnt);
    fill_kernel<<<(NED + 255) / 256, 256, 0, stream>>>(ei, cnt, srcS);

    // ---- precision conversions ----
    cvt_x_kernel<<<12500, 256, 0, stream>>>(x, xb);          // 12.8M floats
    cvt_w_kernel<<<192, 256, 0, stream>>>(W1, W2, W1t, W2t);

    // ---- layer 1: z = A~ x  (bf16 gather), h = relu(z@W1 + b1) ----
    gather128b<<<(NND * 64) / 256 + 1, 256, 0, stream>>>(offs, srcS, dinv, xb, zb);
    gemm_mfma<128, 128, 2, 2, 0><<<dim3(782, 2), 256, 0, stream>>>(
        (const u16*)zb, W1t, b1, nullptr, hb, nullptr, NND, 256, 128);

    // ---- layer 2: xw2 = h@W2 (bf16), out = dinv^2*xw2 + b2, then gather ----
    gemm_mfma<256, 64, 4, 1, 1><<<dim3(391, 1), 256, 0, stream>>>(
        hb, W2t, b2, dinv, xwb, out, NND, 64, 256);
    gather64b<<<(NND * 64) / 256 + 1, 256, 0, stream>>>(offs, srcS, dinv, xwb, out);
}

// Round 5
// 211.018 us; speedup vs baseline: 13.7226x; 1.3323x over previous
//
#include <hip/hip_runtime.h>
#include <cstdint>
#include <cstddef>

#define NND 100000
#define NED 640000
#define NSCAN_B 98          // ceil(NND/1024)

typedef unsigned int u32;
typedef unsigned short u16;
typedef __attribute__((ext_vector_type(8))) short bf16x8;
typedef __attribute__((ext_vector_type(4))) float f32x4;

// ---------------------------------------------------------------------------
// helpers: fp32 <-> bf16 (RNE), async global->LDS 16B
// ---------------------------------------------------------------------------
__device__ __forceinline__ u16 f2b(float f) {
    u32 u = __float_as_uint(f);
    return (u16)((u + 0x7fffu + ((u >> 16) & 1u)) >> 16);
}
__device__ __forceinline__ float b2f(u16 b) {
    return __uint_as_float(((u32)b) << 16);
}
__device__ __forceinline__ u32 pack2(float a, float b) {
    return (u32)f2b(a) | ((u32)f2b(b) << 16);
}
__device__ __forceinline__ void gload16(u16* lds, const u16* g) {
    __builtin_amdgcn_global_load_lds(
        (const __attribute__((address_space(1))) u32*)g,
        (__attribute__((address_space(3))) u32*)lds,
        16, 0, 0);
}

// ---------------------------------------------------------------------------
// degree count (int) and dinv
// ---------------------------------------------------------------------------
__global__ __launch_bounds__(256)
void deg_kernel(const int* __restrict__ ei, int* __restrict__ cnt) {
    const int e = blockIdx.x * 256 + threadIdx.x;
    if (e < NED) atomicAdd(&cnt[ei[NED + e]], 1);
}

__global__ __launch_bounds__(256)
void dinv_kernel(const int* __restrict__ cnt, float* __restrict__ dinv) {
    const int i = blockIdx.x * 256 + threadIdx.x;
    if (i < NND) dinv[i] = rsqrtf(1.0f + (float)cnt[i]);
}

// ---------------------------------------------------------------------------
// exclusive scan of cnt[NND] -> offs[NND+1]
// ---------------------------------------------------------------------------
__global__ __launch_bounds__(256)
void scanA(const int* __restrict__ cnt, int* __restrict__ offs, int* __restrict__ bsum) {
    __shared__ int s[256];
    const int t = threadIdx.x;
    const int base = blockIdx.x * 1024 + t * 4;
    int c0 = (base + 0 < NND) ? cnt[base + 0] : 0;
    int c1 = (base + 1 < NND) ? cnt[base + 1] : 0;
    int c2 = (base + 2 < NND) ? cnt[base + 2] : 0;
    int c3 = (base + 3 < NND) ? cnt[base + 3] : 0;
    const int local = c0 + c1 + c2 + c3;
    s[t] = local;
    __syncthreads();
    for (int off = 1; off < 256; off <<= 1) {
        int v = (t >= off) ? s[t - off] : 0;
        __syncthreads();
        s[t] += v;
        __syncthreads();
    }
    const int excl = s[t] - local;
    if (t == 255) bsum[blockIdx.x] = s[255];
    if (base + 0 < NND) offs[base + 0] = excl;
    if (base + 1 < NND) offs[base + 1] = excl + c0;
    if (base + 2 < NND) offs[base + 2] = excl + c0 + c1;
    if (base + 3 < NND) offs[base + 3] = excl + c0 + c1 + c2;
}

__global__ __launch_bounds__(64)
void scanB(int* __restrict__ bsum, int* __restrict__ offs) {
    if (threadIdx.x == 0) {
        int run = 0;
        for (int b = 0; b < NSCAN_B; ++b) { int v = bsum[b]; bsum[b] = run; run += v; }
        offs[NND] = NED;
    }
}

__global__ __launch_bounds__(256)
void scanC(int* __restrict__ offs, const int* __restrict__ bsum, int* __restrict__ cursor) {
    const int i = blockIdx.x * 256 + threadIdx.x;
    if (i < NND) {
        const int v = offs[i] + bsum[i >> 10];
        offs[i] = v;
        cursor[i] = v;
    }
}

// fill CSR sorted by dst; also precompute edge weight dinv[src]*dinv[dst]
__global__ __launch_bounds__(256)
void fill_kernel(const int* __restrict__ ei, const float* __restrict__ dinv,
                 int* __restrict__ cursor, int* __restrict__ srcS,
                 float* __restrict__ wtS) {
    const int e = blockIdx.x * 256 + threadIdx.x;
    if (e < NED) {
        const int src = ei[e], dst = ei[NED + e];
        const int p = atomicAdd(&cursor[dst], 1);
        srcS[p] = src;
        wtS[p]  = dinv[src] * dinv[dst];
    }
}

// ---------------------------------------------------------------------------
// conversions: x -> bf16 ; W1,W2 -> transposed bf16 (Wt[n][k])
// ---------------------------------------------------------------------------
__global__ __launch_bounds__(256)
void cvt_x_kernel(const float* __restrict__ x, u32* __restrict__ xb) {
    const int i = blockIdx.x * 256 + threadIdx.x;      // exactly 3,200,000 threads
    const float4 v = *(const float4*)&x[(size_t)i * 4];
    xb[(size_t)i * 2 + 0] = pack2(v.x, v.y);
    xb[(size_t)i * 2 + 1] = pack2(v.z, v.w);
}

__global__ __launch_bounds__(256)
void cvt_w_kernel(const float* __restrict__ W1, const float* __restrict__ W2,
                  u16* __restrict__ W1t, u16* __restrict__ W2t) {
    const int i = blockIdx.x * 256 + threadIdx.x;      // 49152 threads
    if (i < 128 * 256) {
        const int k = i >> 8, n = i & 255;
        W1t[n * 128 + k] = f2b(W1[i]);
    } else {
        const int j = i - 128 * 256;                   // j < 256*64
        const int k = j >> 6, n = j & 63;
        W2t[n * 256 + k] = f2b(W2[j]);
    }
}

// ---------------------------------------------------------------------------
// CSR gather (bf16), 8-wide predicated edge groups for MLP.
// z[d] = dinv[d]^2*x[d] + sum_e wt[e]*x[src[e]]
// ---------------------------------------------------------------------------
__global__ __launch_bounds__(256)
void gather128b(const int* __restrict__ offs, const int* __restrict__ srcS,
                const float* __restrict__ wtS, const float* __restrict__ dinv,
                const u32* __restrict__ xb, u32* __restrict__ zb) {
    const int d    = (blockIdx.x * 256 + threadIdx.x) >> 6;
    const int lane = threadIdx.x & 63;
    if (d >= NND) return;
    const int beg = offs[d], end = offs[d + 1];
    const float dd = dinv[d];
    const u32 s = xb[(size_t)d * 64 + lane];
    float ax = b2f((u16)s) * dd * dd;
    float ay = b2f((u16)(s >> 16)) * dd * dd;
    for (int e = beg; e < end; e += 8) {
        int si[8]; float wi[8]; u32 vi[8];
        #pragma unroll
        for (int j = 0; j < 8; ++j) {
            const int ee = e + j;
            const int ec = (ee < end) ? ee : (end - 1);
            si[j] = srcS[ec];
            wi[j] = (ee < end) ? wtS[ec] : 0.0f;
        }
        #pragma unroll
        for (int j = 0; j < 8; ++j)
            vi[j] = xb[(size_t)si[j] * 64 + lane];
        #pragma unroll
        for (int j = 0; j < 8; ++j) {
            ax = fmaf(wi[j], b2f((u16)vi[j]), ax);
            ay = fmaf(wi[j], b2f((u16)(vi[j] >> 16)), ay);
        }
    }
    zb[(size_t)d * 64 + lane] = pack2(ax, ay);
}

// out[d] += sum_e wt[e]*xw2[src[e]]   (out pre-init by gemm2 epilogue; xw2 bf16)
__global__ __launch_bounds__(256)
void gather64b(const int* __restrict__ offs, const int* __restrict__ srcS,
               const float* __restrict__ wtS,
               const u16* __restrict__ xwb, float* __restrict__ out) {
    const int d    = (blockIdx.x * 256 + threadIdx.x) >> 6;
    const int lane = threadIdx.x & 63;
    if (d >= NND) return;
    const int beg = offs[d], end = offs[d + 1];
    float* p = &out[(size_t)d * 64 + lane];
    float acc = *p;
    for (int e = beg; e < end; e += 8) {
        int si[8]; float wi[8]; u16 vi[8];
        #pragma unroll
        for (int j = 0; j < 8; ++j) {
            const int ee = e + j;
            const int ec = (ee < end) ? ee : (end - 1);
            si[j] = srcS[ec];
            wi[j] = (ee < end) ? wtS[ec] : 0.0f;
        }
        #pragma unroll
        for (int j = 0; j < 8; ++j)
            vi[j] = xwb[(size_t)si[j] * 64 + lane];
        #pragma unroll
        for (int j = 0; j < 8; ++j)
            acc = fmaf(wi[j], b2f(vi[j]), acc);
    }
    *p = acc;
}

// ---------------------------------------------------------------------------
// bf16 MFMA GEMM: C = A[M][K] @ Bt[N][K]^T, 4 waves, 64x64 per wave, BK=32.
// EPI 0: O1(bf16) = relu(acc + bias[col])                        (layer-1 h)
// EPI 1: O1(bf16) = acc ; O2(fp32) = dinv[row]^2*acc + bias[col] (xw2 + out-init)
// ---------------------------------------------------------------------------
template<int BM, int BN, int WM, int WN, int EPI>
__global__ __launch_bounds__(256)
void gemm_mfma(const u16* __restrict__ A, const u16* __restrict__ Bt,
               const float* __restrict__ bias, const float* __restrict__ dinv,
               void* __restrict__ O1, float* __restrict__ O2,
               int M, int N, int K)
{
    __shared__ __align__(16) u16 As[BM * 32];
    __shared__ __align__(16) u16 Bs[BN * 32];
    const int tid  = threadIdx.x;
    const int lane = tid & 63;
    const int wid  = tid >> 6;
    const int wm   = wid % WM;
    const int wn   = wid / WM;
    const int row0 = blockIdx.x * BM;
    const int col0 = blockIdx.y * BN;
    const int wrow0 = wm * 64, wcol0 = wn * 64;

    f32x4 acc[4][4];
    #pragma unroll
    for (int i = 0; i < 4; ++i)
        #pragma unroll
        for (int j = 0; j < 4; ++j) acc[i][j] = (f32x4){0.f, 0.f, 0.f, 0.f};

    const int lr = lane >> 2;          // 0..15: row within 16-row load chunk
    const int lk = (lane & 3) * 8;     // k-element offset (16B granule)

    for (int kt = 0; kt < K; kt += 32) {
        #pragma unroll
        for (int j = 0; j < BM / 64; ++j) {
            const int li = wid * (BM / 64) + j;            // 16 rows per load
            const int r  = li * 16 + lr;
            const int rg = (row0 + r < M) ? (row0 + r) : (M - 1);
            gload16(&As[li * 512], &A[(size_t)rg * K + kt + lk]);
        }
        #pragma unroll
        for (int j = 0; j < BN / 64; ++j) {
            const int li = wid * (BN / 64) + j;
            const int n  = li * 16 + lr;
            gload16(&Bs[li * 512], &Bt[(size_t)(col0 + n) * K + kt + lk]);
        }
        __syncthreads();

        bf16x8 af[4], bfr[4];
        #pragma unroll
        for (int mi = 0; mi < 4; ++mi)
            af[mi] = *(const bf16x8*)&As[(wrow0 + mi * 16 + (lane & 15)) * 32 + (lane >> 4) * 8];
        #pragma unroll
        for (int ni = 0; ni < 4; ++ni)
            bfr[ni] = *(const bf16x8*)&Bs[(wcol0 + ni * 16 + (lane & 15)) * 32 + (lane >> 4) * 8];
        #pragma unroll
        for (int mi = 0; mi < 4; ++mi)
            #pragma unroll
            for (int ni = 0; ni < 4; ++ni)
                acc[mi][ni] = __builtin_amdgcn_mfma_f32_16x16x32_bf16(
                    af[mi], bfr[ni], acc[mi][ni], 0, 0, 0);
        __syncthreads();
    }

    const int rb = (lane >> 4) * 4;
    const int cl = lane & 15;
    #pragma unroll
    for (int mi = 0; mi < 4; ++mi) {
        #pragma unroll
        for (int r = 0; r < 4; ++r) {
            const int row = row0 + wrow0 + mi * 16 + rb + r;
            if (row >= M) continue;
            #pragma unroll
            for (int ni = 0; ni < 4; ++ni) {
                const int col = col0 + wcol0 + ni * 16 + cl;
                const float v = acc[mi][ni][r];
                if constexpr (EPI == 0) {
                    ((u16*)O1)[(size_t)row * N + col] = f2b(fmaxf(v + bias[col], 0.f));
                } else {
                    ((u16*)O1)[(size_t)row * N + col] = f2b(v);
                    const float dd = dinv[row];
                    O2[(size_t)row * N + col] = fmaf(dd * dd, v, bias[col]);
                }
            }
        }
    }
}

// ---------------------------------------------------------------------------
extern "C" void kernel_launch(void* const* d_in, const int* in_sizes, int n_in,
                              void* d_out, int out_size, void* d_ws, size_t ws_size,
                              hipStream_t stream)
{
    const float* x  = (const float*)d_in[0];
    const int*   ei = (const int*)d_in[1];   // [2, E]: src row then dst row
    const float* W1 = (const float*)d_in[2];
    const float* b1 = (const float*)d_in[3];
    const float* W2 = (const float*)d_in[4];
    const float* b2 = (const float*)d_in[5];
    float* out = (float*)d_out;

    // workspace layout (bytes, all 128-aligned):
    char* ws = (char*)d_ws;
    float* dinv = (float*)(ws + 0);            //    400,000 -> 400,128
    int*   cnt  = (int*)  (ws + 400128);       //    400,000 -> 800,128 (reused as cursor)
    int*   offs = (int*)  (ws + 800128);       //    400,004 -> 1,200,256
    int*   bsum = (int*)  (ws + 1200256);      //        512 -> 1,200,768
    int*   srcS = (int*)  (ws + 1200768);      //  2,560,000 -> 3,760,768
    float* wtS  = (float*)(ws + 3760768);      //  2,560,000 -> 6,320,768
    u32*   xb   = (u32*)  (ws + 6320768);      // 25,600,000 -> 31,920,768  (x bf16)
    u32*   zb   = (u32*)  (ws + 31920768);     // 25,600,000 -> 57,520,768  (Ax bf16)
    u16*   hb   = (u16*)  (ws + 57520768);     // 51,200,000 -> 108,720,768 (h bf16)
    u16*   W1t  = (u16*)  (ws + 108720768);    //     65,536 -> 108,786,304
    u16*   W2t  = (u16*)  (ws + 108786304);    //     32,768 -> 108,819,072
    u16*   xwb  = (u16*)  (ws + 108819072);    // 12,800,000 -> 121,619,072 (xw2 bf16)

    // ---- CSR build + dinv + edge weights ----
    hipMemsetAsync(cnt, 0, NND * sizeof(int), stream);
    deg_kernel<<<(NED + 255) / 256, 256, 0, stream>>>(ei, cnt);
    dinv_kernel<<<(NND + 255) / 256, 256, 0, stream>>>(cnt, dinv);
    scanA<<<NSCAN_B, 256, 0, stream>>>(cnt, offs, bsum);
    scanB<<<1, 64, 0, stream>>>(bsum, offs);
    scanC<<<(NND + 255) / 256, 256, 0, stream>>>(offs, bsum, cnt);
    fill_kernel<<<(NED + 255) / 256, 256, 0, stream>>>(ei, dinv, cnt, srcS, wtS);

    // ---- precision conversions ----
    cvt_x_kernel<<<12500, 256, 0, stream>>>(x, xb);          // 12.8M floats
    cvt_w_kernel<<<192, 256, 0, stream>>>(W1, W2, W1t, W2t);

    // ---- layer 1: z = A~ x  (bf16 gather), h = relu(z@W1 + b1) ----
    gather128b<<<(NND * 64) / 256 + 1, 256, 0, stream>>>(offs, srcS, wtS, dinv, xb, zb);
    gemm_mfma<128, 128, 2, 2, 0><<<dim3(782, 2), 256, 0, stream>>>(
        (const u16*)zb, W1t, b1, nullptr, hb, nullptr, NND, 256, 128);

    // ---- layer 2: xw2 = h@W2 (bf16), out = dinv^2*xw2 + b2, then gather ----
    gemm_mfma<256, 64, 4, 1, 1><<<dim3(391, 1), 256, 0, stream>>>(
        hb, W2t, b2, dinv, xwb, out, NND, 64, 256);
    gather64b<<<(NND * 64) / 256 + 1, 256, 0, stream>>>(offs, srcS, wtS, xwb, out);
}